// Round 16
// baseline (115.180 us; speedup 1.0000x reference)
//
#include <hip/hip_runtime.h>

#define K3 27
#define CIN 8
#define COUT 64
#define K3C (K3*CIN)      // 216
#define CC_EPS 1e-12f
#define CHUNK 32
#define RECW 12           // weight record: wab[9] (win-premultiplied) + wc[3]
#define MAXS 8

// ---------------- Kernel 1: per-(point, j-slice) partial B ------------------
// Block = 256 threads = 4 INDEPENDENT waves (no __syncthreads).
// Wave = one unit (i = point, s = slice of the j range). Scan own slice with
// ballot compaction (registers only, no atomics), then R8-proven stage-A/B:
//   stage A: lane<32 computes one slot's geometry -> 12-float LDS record
//   stage B: 8-lane group g, round t reads record t*8+g, 27 FMA, c = channel
// Reduce over groups via shfl, lanes 0-7 store B_w[27][8] to Bpart[unit].
__global__ __launch_bounds__(256, 8)
void cconv_scatter_kernel(const float* __restrict__ features,
                          const float* __restrict__ pos_input,
                          const float* __restrict__ pos_output,
                          const float* __restrict__ extents,
                          float* __restrict__ Bpart,
                          int Ni, int No, int S)
{
    const int tid  = threadIdx.x;
    const int w    = tid >> 6;
    const int lane = tid & 63;
    const int g    = lane >> 3;
    const int c    = lane & 7;
    const int unit = blockIdx.x * 4 + w;

    __shared__ unsigned short      idxs[4][512];
    __shared__ __align__(16) float rec[4][CHUNK][RECW];

    if (unit >= No * S) return;          // safe: no barriers in this kernel
    const int i = unit / S;
    const int s = unit - i * S;

    const float sc = 2.0f / extents[0];
    const float ox = pos_output[i*3+0];
    const float oy = pos_output[i*3+1];
    const float oz = pos_output[i*3+2];

    const int jb = (int)(((long long)Ni * s)       / S);
    const int je = (int)(((long long)Ni * (s + 1)) / S);

    // ---- scan own slice, ballot-compact into private LDS list
    int cnt = 0;
    for (int j0 = jb; j0 < je; j0 += 64) {
        const int j = j0 + lane;
        bool inside = false;
        if (j < je) {
            const float rx = (pos_input[j*3+0]-ox)*sc;
            const float ry = (pos_input[j*3+1]-oy)*sc;
            const float rz = (pos_input[j*3+2]-oz)*sc;
            inside = (rx*rx + ry*ry + rz*rz) < 1.0f;
        }
        const unsigned long long m = __ballot(inside);
        if (inside) {
            const int pre = __popcll(m & ((1ull<<lane)-1ull));
            idxs[w][cnt + pre] = (unsigned short)j;
        }
        cnt += (int)__popcll(m);
    }

    // ---- interp over compacted list, chunks of 32
    float acc[K3];
#pragma unroll
    for (int k = 0; k < K3; ++k) acc[k] = 0.0f;

    for (int cb = 0; cb < cnt; cb += CHUNK) {
        if (lane < CHUNK) {
            const int  slot = cb + lane;
            const bool va   = slot < cnt;
            const int  j    = idxs[w][va ? slot : 0];
            float ab0=0,ab1=0,ab2=0,ab3=0,ab4=0,ab5=0,ab6=0,ab7=0,ab8=0;
            float wc0=0,wc1=0,wc2=0;
            if (va) {
                const float rx = (pos_input[j*3+0]-ox)*sc;   // comp0 -> stride 9
                const float ry = (pos_input[j*3+1]-oy)*sc;   // comp1 -> stride 3
                const float rz = (pos_input[j*3+2]-oz)*sc;   // comp2 -> stride 1
                const float r2  = rx*rx + ry*ry + rz*rz;     // < 1 guaranteed
                const float u   = 1.0f - r2;
                const float win = u*u*u;                     // poly6 window
                const float r    = __builtin_amdgcn_sqrtf(fmaxf(r2, CC_EPS));
                const float linf = fmaxf(fmaxf(fabsf(rx), fabsf(ry)), fabsf(rz));
                const float scale = (linf > CC_EPS) ? r*__builtin_amdgcn_rcpf(linf) : 1.0f;
                const float ta = fminf(fmaxf(rx*scale, -1.f), 1.f) + 1.0f;
                const float tb = fminf(fmaxf(ry*scale, -1.f), 1.f) + 1.0f;
                const float tc = fminf(fmaxf(rz*scale, -1.f), 1.f) + 1.0f;
                // 1-D trilinear over 3 bins: t<1:{1-t,t,0}, t>=1:{0,2-t,t-1}
                const float wa0 = fmaxf(1.0f-ta, 0.0f), wa2 = fmaxf(ta-1.0f, 0.0f);
                const float wb0 = fmaxf(1.0f-tb, 0.0f), wb2 = fmaxf(tb-1.0f, 0.0f);
                wc0 = fmaxf(1.0f-tc, 0.0f); wc2 = fmaxf(tc-1.0f, 0.0f);
                const float wa1 = 1.0f - wa0 - wa2;
                const float wb1 = 1.0f - wb0 - wb2;
                wc1 = 1.0f - wc0 - wc2;
                const float a0 = wa0*win, a1 = wa1*win, a2 = wa2*win;
                ab0 = a0*wb0; ab1 = a0*wb1; ab2 = a0*wb2;
                ab3 = a1*wb0; ab4 = a1*wb1; ab5 = a1*wb2;
                ab6 = a2*wb0; ab7 = a2*wb1; ab8 = a2*wb2;
            }
            float* rp = &rec[w][lane][0];
            ((float4*)rp)[0] = make_float4(ab0, ab1, ab2, ab3);
            ((float4*)rp)[1] = make_float4(ab4, ab5, ab6, ab7);
            ((float4*)rp)[2] = make_float4(ab8, wc0, wc1, wc2);
        }
        asm volatile("s_waitcnt lgkmcnt(0)" ::: "memory");
        __builtin_amdgcn_sched_barrier(0);

#pragma unroll
        for (int t = 0; t < CHUNK/8; ++t) {
            const int l    = t*8 + g;
            const int slot = cb + l;
            const float* rp = &rec[w][l][0];
            const float4 r0 = ((const float4*)rp)[0];
            const float4 r1 = ((const float4*)rp)[1];
            const float4 r2 = ((const float4*)rp)[2];
            const int   jj = idxs[w][slot < cnt ? slot : 0];
            const float fv = features[jj*CIN + c];       // rec is zero if invalid
            const float wabv[9] = { r0.x, r0.y, r0.z, r0.w,
                                    r1.x, r1.y, r1.z, r1.w, r2.x };
            const float fcs[3]  = { r2.y*fv, r2.z*fv, r2.w*fv };
#pragma unroll
            for (int ab = 0; ab < 9; ++ab) {
#pragma unroll
                for (int c3 = 0; c3 < 3; ++c3) {
                    acc[ab*3 + c3] = fmaf(wabv[ab], fcs[c3], acc[ab*3 + c3]);
                }
            }
        }
    }

    // reduce over groups (lane bits 3..5); lanes 0-7 hold per-channel sums
#pragma unroll
    for (int k = 0; k < K3; ++k) {
        float v = acc[k];
        v += __shfl_xor(v, 8, 64);
        v += __shfl_xor(v, 16, 64);
        v += __shfl_xor(v, 32, 64);
        acc[k] = v;
    }
    if (lane < 8) {
        float* dst = Bpart + (size_t)unit * K3C;
#pragma unroll
        for (int k = 0; k < K3; ++k) dst[k*CIN + lane] = acc[k];
    }
}

// ---------------- Kernel 2: reduce slices + GEMM + bias + relu --------------
// Block = 256 = 4 waves; wave = one point, lane = output channel f.
__global__ __launch_bounds__(256)
void cconv_gemm_kernel(const float* __restrict__ Bpart,
                       const float* __restrict__ kern,
                       const float* __restrict__ bias,
                       float* __restrict__ out,
                       int No, int S)
{
    const int tid = threadIdx.x;
    const int w   = tid >> 6;
    const int f   = tid & 63;
    const int i   = blockIdx.x * 4 + w;

    __shared__ float Bs[4][K3C];

    if (i >= No) return;   // waves independent; no cross-wave barrier used

    // sum the S slice-partials for this point (coalesced by lane)
    for (int t = f; t < K3C; t += 64) {
        const float* p = Bpart + (size_t)i * S * K3C + t;
        float v = 0.0f;
        for (int s = 0; s < S; ++s) v += p[s * K3C];
        Bs[w][t] = v;
    }
    // same-wave LDS write->read: DS ops in order; compiler inserts lgkmcnt.

    float o = bias[f];
#pragma unroll 3
    for (int k = 0; k < K3; ++k) {
#pragma unroll
        for (int cc = 0; cc < CIN; ++cc) {
            o = fmaf(Bs[w][k*CIN + cc], kern[(k*CIN + cc)*COUT + f], o);
        }
    }
    out[(size_t)i * COUT + f] = fmaxf(o, 0.0f);
}

extern "C" void kernel_launch(void* const* d_in, const int* in_sizes, int n_in,
                              void* d_out, int out_size, void* d_ws, size_t ws_size,
                              hipStream_t stream) {
    const float* features   = (const float*)d_in[0];
    const float* pos_input  = (const float*)d_in[1];
    const float* pos_output = (const float*)d_in[2];
    const float* extents    = (const float*)d_in[3];
    const float* kern       = (const float*)d_in[4];
    const float* bias       = (const float*)d_in[5];
    float* out = (float*)d_out;

    const int Ni = in_sizes[0] / CIN;   // 2048 (slice list cap assumes Ni<=4096)
    const int No = in_sizes[2] / 3;

    // pick slice count S so Bpart fits the workspace
    int S = MAXS;
    while (S > 1 && (size_t)No * S * K3C * sizeof(float) > ws_size) S >>= 1;
    float* Bpart = (float*)d_ws;

    {
        const int units = No * S;
        dim3 block(256);
        dim3 grid((units + 3) / 4);
        cconv_scatter_kernel<<<grid, block, 0, stream>>>(features, pos_input,
                                                         pos_output, extents,
                                                         Bpart, Ni, No, S);
    }
    {
        dim3 block(256);
        dim3 grid((No + 3) / 4);
        cconv_gemm_kernel<<<grid, block, 0, stream>>>(Bpart, kern, bias, out, No, S);
    }
}

// Round 17
// 99.027 us; speedup vs baseline: 1.1631x; 1.1631x over previous
//
#include <hip/hip_runtime.h>

#define K3 27
#define CIN 8
#define COUT 64
#define CC_EPS 1e-12f
#define CHUNK 32
#define RECW 12   // weight record: wab[9] (win-premultiplied a*b) + wc[3]

// Block = 256 threads = 4 waves = ONE output point.  (R10 structure)
// Phase 1: cooperative ballot-compaction of inside-ball j's into shared idx[].
// Phase 2 per wave, chunks of 32 slots (stride 128):
//   prefetch: the 4 rounds' idx + feature gathers issued at chunk top so
//             global latency hides under stage A geometry.
//   stage A: lane(<32) computes ONE slot's geometry -> 12-float LDS record.
//   stage B: 8-lane group g, round t consumes record l=t*8+g (conflict-free
//            b128 broadcast reads), 27 FMA per channel-lane.
//   Same-wave ds_write -> ds_read is ordered by the compiler's own lgkmcnt
//   (DS ops in-order per wave; LDS dependence kept) -- NO asm fence.
// Epilogue: shfl-reduce over groups, cross-wave sum into Bsh[0], 4-way k-split
// GEMM, relu, store. part[] aliases idx[] to keep LDS at ~13.7 KB.
__global__ __launch_bounds__(256, 8)
void cconv_fused_kernel(const float* __restrict__ features,
                        const float* __restrict__ pos_input,
                        const float* __restrict__ pos_output,
                        const float* __restrict__ extents,
                        const float* __restrict__ kern,
                        const float* __restrict__ bias,
                        float* __restrict__ out,
                        int Ni, int No)
{
    const int tid  = threadIdx.x;
    const int w    = tid >> 6;        // wave 0..3
    const int lane = tid & 63;
    const int g    = lane >> 3;       // 8-lane group 0..7
    const int c    = lane & 7;        // input channel
    const int i    = blockIdx.x;      // output point

    // carved LDS: idx[2048] ushort (aliased by part[4][COUT] in epilogue),
    // wrec[4][CHUNK][RECW] f32, Bsh[4][K3][CIN] f32
    __shared__ __align__(16) char smem[4096 + 4*CHUNK*RECW*4 + 4*K3*CIN*4];
    unsigned short* idx  = (unsigned short*)smem;
    float*          part = (float*)smem;                            // aliases idx
    float*          wrec = (float*)(smem + 4096);
    float*          Bsh  = (float*)(smem + 4096 + 4*CHUNK*RECW*4);
    __shared__ int cnt_sh;

    if (tid == 0) cnt_sh = 0;
    __syncthreads();

    const float s  = 2.0f / extents[0];
    const float ox = pos_output[i*3+0];
    const float oy = pos_output[i*3+1];
    const float oz = pos_output[i*3+2];

    // ---------------- Phase 1: cooperative ballot compaction ----------------
    for (int j0 = w*64; j0 < Ni; j0 += 256) {
        const int j = j0 + lane;
        bool inside = false;
        if (j < Ni) {
            const float rx = (pos_input[j*3+0]-ox)*s;
            const float ry = (pos_input[j*3+1]-oy)*s;
            const float rz = (pos_input[j*3+2]-oz)*s;
            inside = (rx*rx + ry*ry + rz*rz) < 1.0f;
        }
        const unsigned long long m = __ballot(inside);
        const int nin = (int)__popcll(m);
        int base = 0;
        if (lane == 0 && nin) base = atomicAdd(&cnt_sh, nin);
        base = __shfl(base, 0, 64);
        if (inside) {
            const int pre = __popcll(m & ((1ull<<lane)-1ull));
            idx[base+pre] = (unsigned short)j;
        }
    }
    __syncthreads();
    const int total = cnt_sh;

    // ---------------- Phase 2: stage-A/stage-B dedup over compacted list ----
    float acc[K3];
#pragma unroll
    for (int k = 0; k < K3; ++k) acc[k] = 0.0f;

    for (int cb = w*CHUNK; cb < total; cb += 4*CHUNK) {
        // ---- prefetch the 4 rounds' stage-B gathers (independent of stage A)
        float fv[4];
#pragma unroll
        for (int t = 0; t < 4; ++t) {
            const int slot = cb + t*8 + g;
            const int jj   = idx[(slot < total) ? slot : 0];
            fv[t] = features[jj*CIN + c];   // rec weight is zero if slot invalid
        }

        // ---- stage A: one lane per slot, geometry -> 12-float record
        if (lane < CHUNK) {
            const int  slot = cb + lane;
            const bool va   = slot < total;
            const int  j    = idx[va ? slot : 0];
            float ab0=0,ab1=0,ab2=0,ab3=0,ab4=0,ab5=0,ab6=0,ab7=0,ab8=0;
            float wc0=0,wc1=0,wc2=0;
            if (va) {
                const float rx = (pos_input[j*3+0]-ox)*s;   // comp0 -> stride 9
                const float ry = (pos_input[j*3+1]-oy)*s;   // comp1 -> stride 3
                const float rz = (pos_input[j*3+2]-oz)*s;   // comp2 -> stride 1
                const float r2  = rx*rx + ry*ry + rz*rz;    // < 1 guaranteed
                const float u   = 1.0f - r2;
                const float win = u*u*u;                    // poly6 window
                const float r    = __builtin_amdgcn_sqrtf(fmaxf(r2, CC_EPS));
                const float linf = fmaxf(fmaxf(fabsf(rx), fabsf(ry)), fabsf(rz));
                const float scale = (linf > CC_EPS) ? r*__builtin_amdgcn_rcpf(linf) : 1.0f;
                const float ta = fminf(fmaxf(rx*scale, -1.f), 1.f) + 1.0f;
                const float tb = fminf(fmaxf(ry*scale, -1.f), 1.f) + 1.0f;
                const float tc = fminf(fmaxf(rz*scale, -1.f), 1.f) + 1.0f;
                // 1-D trilinear over 3 bins: t<1:{1-t,t,0}, t>=1:{0,2-t,t-1}
                const float wa0 = fmaxf(1.0f-ta, 0.0f), wa2 = fmaxf(ta-1.0f, 0.0f);
                const float wb0 = fmaxf(1.0f-tb, 0.0f), wb2 = fmaxf(tb-1.0f, 0.0f);
                wc0 = fmaxf(1.0f-tc, 0.0f); wc2 = fmaxf(tc-1.0f, 0.0f);
                const float wa1 = 1.0f - wa0 - wa2;
                const float wb1 = 1.0f - wb0 - wb2;
                wc1 = 1.0f - wc0 - wc2;
                const float a0 = wa0*win, a1 = wa1*win, a2 = wa2*win;
                ab0 = a0*wb0; ab1 = a0*wb1; ab2 = a0*wb2;
                ab3 = a1*wb0; ab4 = a1*wb1; ab5 = a1*wb2;
                ab6 = a2*wb0; ab7 = a2*wb1; ab8 = a2*wb2;
            }
            float* rec = wrec + (w*CHUNK + lane)*RECW;
            ((float4*)rec)[0] = make_float4(ab0, ab1, ab2, ab3);
            ((float4*)rec)[1] = make_float4(ab4, ab5, ab6, ab7);
            ((float4*)rec)[2] = make_float4(ab8, wc0, wc1, wc2);
        }
        // same-wave ds_write -> ds_read: DS ops execute in order per wave and
        // the compiler keeps LDS dependences -- no fence needed.

        // ---- stage B: group g, round t consumes record l = t*8+g
#pragma unroll
        for (int t = 0; t < 4; ++t) {
            const int l = t*8 + g;
            const float* rec = wrec + (w*CHUNK + l)*RECW;
            const float4 r0 = ((const float4*)rec)[0];
            const float4 r1 = ((const float4*)rec)[1];
            const float4 r2 = ((const float4*)rec)[2];
            const float fvt = fv[t];
            const float wabv[9] = { r0.x, r0.y, r0.z, r0.w,
                                    r1.x, r1.y, r1.z, r1.w, r2.x };
            const float fcs[3]  = { r2.y*fvt, r2.z*fvt, r2.w*fvt };
#pragma unroll
            for (int ab = 0; ab < 9; ++ab) {
#pragma unroll
                for (int c3 = 0; c3 < 3; ++c3) {
                    acc[ab*3 + c3] = fmaf(wabv[ab], fcs[c3], acc[ab*3 + c3]);
                }
            }
        }
    }

    // within-wave reduce over groups (lane bits 3..5)
#pragma unroll
    for (int k = 0; k < K3; ++k) {
        float v = acc[k];
        v += __shfl_xor(v, 8, 64);
        v += __shfl_xor(v, 16, 64);
        v += __shfl_xor(v, 32, 64);
        acc[k] = v;
    }
    if (g == 0) {
#pragma unroll
        for (int k = 0; k < K3; ++k) Bsh[(w*K3 + k)*CIN + c] = acc[k];
    }
    __syncthreads();

    // cross-wave sum into Bsh[0]
    if (tid < K3*CIN) {
        const int k  = tid >> 3;
        const int cc = tid & 7;
        Bsh[k*CIN + cc] = Bsh[k*CIN + cc]
                        + Bsh[(K3   + k)*CIN + cc]
                        + Bsh[(2*K3 + k)*CIN + cc]
                        + Bsh[(3*K3 + k)*CIN + cc];
    }
    __syncthreads();

    // ---------------- Epilogue: out = relu(B . kernel + bias), 4-way k-split
    {
        const int kb = w*7;
        const int ke = (kb + 7 < K3) ? kb + 7 : K3;
        float o = 0.0f;
        for (int k = kb; k < ke; ++k) {
#pragma unroll
            for (int cc = 0; cc < CIN; ++cc) {
                o = fmaf(Bsh[k*CIN + cc], kern[(k*CIN + cc)*COUT + lane], o);
            }
        }
        part[w*COUT + lane] = o;    // part aliases idx (idx dead after phase 2)
    }
    __syncthreads();

    if (tid < COUT) {
        const float o = bias[tid] + part[tid] + part[COUT + tid]
                      + part[2*COUT + tid] + part[3*COUT + tid];
        out[i*COUT + tid] = fmaxf(o, 0.0f);
    }
}

extern "C" void kernel_launch(void* const* d_in, const int* in_sizes, int n_in,
                              void* d_out, int out_size, void* d_ws, size_t ws_size,
                              hipStream_t stream) {
    const float* features   = (const float*)d_in[0];
    const float* pos_input  = (const float*)d_in[1];
    const float* pos_output = (const float*)d_in[2];
    const float* extents    = (const float*)d_in[3];
    const float* kern       = (const float*)d_in[4];
    const float* bias       = (const float*)d_in[5];
    float* out = (float*)d_out;

    const int Ni = in_sizes[0] / CIN;   // 2048 (idx cap assumes Ni <= 2048)
    const int No = in_sizes[2] / 3;

    dim3 block(256);
    dim3 grid(No);
    cconv_fused_kernel<<<grid, block, 0, stream>>>(features, pos_input, pos_output,
                                                   extents, kern, bias, out, Ni, No);
}